// Round 1
// baseline (3351.457 us; speedup 1.0000x reference)
//
#include <hip/hip_runtime.h>
#include <cstddef>

// ---------------------------------------------------------------------------
// FastGCN: 2-layer GCN forward.
//   deg -> dis = rsqrt(deg); H = x@W1; A1 = scatter(norm*H) + dis^2*H (self);
//   X2 = relu(A1+b1); H2 = X2@W2; out = scatter(norm*H2) + dis^2*H2 + b2
// ---------------------------------------------------------------------------

__global__ __launch_bounds__(256) void k_deg(const int* __restrict__ dst,
                                             int* __restrict__ cnt, int E) {
    int e = blockIdx.x * 256 + threadIdx.x;
    if (e < E) atomicAdd(&cnt[dst[e]], 1);
}

__global__ __launch_bounds__(256) void k_dis(const int* __restrict__ cnt,
                                             float* __restrict__ dis, int n) {
    int i = blockIdx.x * 256 + threadIdx.x;
    if (i < n) dis[i] = rsqrtf((float)(cnt[i] + 1));   // +1 = self-loop
}

// One row per thread; W addresses are wave-uniform -> scalar loads; acc in VGPRs.
// K fixed at 128. Computes cols [blockIdx.y*MC, +MC) of out[row] (leading dim M).
template <int MC>
__global__ __launch_bounds__(256) void k_gemm(const float* __restrict__ X,
                                              const float* __restrict__ W,
                                              float* __restrict__ out,
                                              int n, int M) {
    int row = blockIdx.x * 256 + threadIdx.x;
    int colbase = blockIdx.y * MC;
    if (row >= n) return;
    const float4* xr = (const float4*)(X + (size_t)row * 128);
    float acc[MC];
#pragma unroll
    for (int j = 0; j < MC; ++j) acc[j] = 0.f;
    for (int k4 = 0; k4 < 32; ++k4) {
        float4 xv = xr[k4];
        const float* w0 = W + (size_t)(k4 * 4) * M + colbase;
#pragma unroll
        for (int j = 0; j < MC; ++j) acc[j] = fmaf(xv.x, w0[j], acc[j]);
#pragma unroll
        for (int j = 0; j < MC; ++j) acc[j] = fmaf(xv.y, w0[M + j], acc[j]);
#pragma unroll
        for (int j = 0; j < MC; ++j) acc[j] = fmaf(xv.z, w0[2 * M + j], acc[j]);
#pragma unroll
        for (int j = 0; j < MC; ++j) acc[j] = fmaf(xv.w, w0[3 * M + j], acc[j]);
    }
    float* o = out + (size_t)row * M + colbase;
#pragma unroll
    for (int j = 0; j < MC; ++j) o[j] = acc[j];
}

// A[i][:] = H[i][:] * dis[i]^2   (self-loop init, 128 cols, float4 lanes)
__global__ __launch_bounds__(256) void k_agg1_init(const float* __restrict__ H,
                                                   const float* __restrict__ dis,
                                                   float* __restrict__ A, int n) {
    int t = blockIdx.x * 256 + threadIdx.x;
    if (t >= n * 32) return;
    int i = t >> 5;
    float d2 = dis[i] * dis[i];
    float4 h = ((const float4*)H)[t];
    float4 r = make_float4(h.x * d2, h.y * d2, h.z * d2, h.w * d2);
    ((float4*)A)[t] = r;
}

// 32 lanes per edge, float4 each: A[dst] += dis[s]*dis[d] * H[src]
__global__ __launch_bounds__(256) void k_agg1_edges(const float* __restrict__ H,
                                                    const float* __restrict__ dis,
                                                    const int* __restrict__ src,
                                                    const int* __restrict__ dst,
                                                    float* __restrict__ A, int E) {
    int t = blockIdx.x * 256 + threadIdx.x;
    if (t >= E * 32) return;
    int e = t >> 5, l = t & 31;
    int s = src[e], d = dst[e];
    float nrm = dis[s] * dis[d];
    float4 h = ((const float4*)H)[(size_t)s * 32 + l];
    float* a = A + (size_t)d * 128 + l * 4;
    atomicAdd(a + 0, nrm * h.x);
    atomicAdd(a + 1, nrm * h.y);
    atomicAdd(a + 2, nrm * h.z);
    atomicAdd(a + 3, nrm * h.w);
}

// X2 = relu(A + b1)
__global__ __launch_bounds__(256) void k_relu_bias(const float* __restrict__ A,
                                                   const float* __restrict__ b1,
                                                   float* __restrict__ X2, int n) {
    int t = blockIdx.x * 256 + threadIdx.x;
    if (t >= n * 32) return;
    int j4 = t & 31;
    float4 a = ((const float4*)A)[t];
    float4 b = ((const float4*)b1)[j4];
    float4 r;
    r.x = fmaxf(a.x + b.x, 0.f);
    r.y = fmaxf(a.y + b.y, 0.f);
    r.z = fmaxf(a.z + b.z, 0.f);
    r.w = fmaxf(a.w + b.w, 0.f);
    ((float4*)X2)[t] = r;
}

// out[i][:] = H2[i][:] * dis[i]^2 + b2   (40 cols = 10 float4)
__global__ __launch_bounds__(256) void k_agg2_init(const float* __restrict__ H2,
                                                   const float* __restrict__ dis,
                                                   const float* __restrict__ b2,
                                                   float* __restrict__ out, int n) {
    int t = blockIdx.x * 256 + threadIdx.x;
    if (t >= n * 10) return;
    int i = t / 10, l = t - i * 10;
    float d2 = dis[i] * dis[i];
    float4 h = ((const float4*)H2)[t];
    float4 b = ((const float4*)b2)[l];
    float4 r = make_float4(fmaf(h.x, d2, b.x), fmaf(h.y, d2, b.y),
                           fmaf(h.z, d2, b.z), fmaf(h.w, d2, b.w));
    ((float4*)out)[t] = r;
}

// 10 float4-lanes per edge: out[dst] += norm * H2[src]
__global__ __launch_bounds__(256) void k_agg2_edges(const float* __restrict__ H2,
                                                    const float* __restrict__ dis,
                                                    const int* __restrict__ src,
                                                    const int* __restrict__ dst,
                                                    float* __restrict__ out, int E) {
    int t = blockIdx.x * 256 + threadIdx.x;
    if (t >= E * 10) return;
    int e = t / 10, l = t - e * 10;
    int s = src[e], d = dst[e];
    float nrm = dis[s] * dis[d];
    float4 h = ((const float4*)H2)[(size_t)s * 10 + l];
    float* o = out + (size_t)d * 40 + l * 4;
    atomicAdd(o + 0, nrm * h.x);
    atomicAdd(o + 1, nrm * h.y);
    atomicAdd(o + 2, nrm * h.z);
    atomicAdd(o + 3, nrm * h.w);
}

static inline int cdiv(long long a, long long b) { return (int)((a + b - 1) / b); }

extern "C" void kernel_launch(void* const* d_in, const int* in_sizes, int n_in,
                              void* d_out, int out_size, void* d_ws, size_t ws_size,
                              hipStream_t stream) {
    const float* x  = (const float*)d_in[0];
    const float* W1 = (const float*)d_in[1];
    const float* b1 = (const float*)d_in[2];
    const float* W2 = (const float*)d_in[3];
    const float* b2 = (const float*)d_in[4];
    const int*   ei = (const int*)d_in[5];

    const int n = in_sizes[0] / 128;   // 170000
    const int E = in_sizes[5] / 2;     // 1200000
    const int* srcv = ei;
    const int* dstv = ei + E;
    float* out = (float*)d_out;

    // workspace carve-up (256B-aligned)
    char* w = (char*)d_ws;
    size_t off = 0;
    auto carve = [&](size_t bytes) {
        void* p = w + off;
        off += (bytes + 255) & ~(size_t)255;
        return p;
    };
    int*   cnt  = (int*)carve((size_t)n * 4);
    float* dis  = (float*)carve((size_t)n * 4);
    float* Hbuf = (float*)carve((size_t)n * 128 * 4);  // H1, then X2
    float* Abuf = (float*)carve((size_t)n * 128 * 4);  // A1, then H2
    (void)ws_size;

    hipMemsetAsync(cnt, 0, (size_t)n * 4, stream);
    k_deg<<<cdiv(E, 256), 256, 0, stream>>>(dstv, cnt, E);
    k_dis<<<cdiv(n, 256), 256, 0, stream>>>(cnt, dis, n);

    // layer 1
    dim3 g1(cdiv(n, 256), 128 / 32);
    k_gemm<32><<<g1, 256, 0, stream>>>(x, W1, Hbuf, n, 128);
    k_agg1_init<<<cdiv((long long)n * 32, 256), 256, 0, stream>>>(Hbuf, dis, Abuf, n);
    k_agg1_edges<<<cdiv((long long)E * 32, 256), 256, 0, stream>>>(Hbuf, dis, srcv, dstv, Abuf, E);
    k_relu_bias<<<cdiv((long long)n * 32, 256), 256, 0, stream>>>(Abuf, b1, Hbuf, n);

    // layer 2
    dim3 g2(cdiv(n, 256), 1);
    k_gemm<40><<<g2, 256, 0, stream>>>(Hbuf, W2, Abuf, n, 40);
    k_agg2_init<<<cdiv((long long)n * 10, 256), 256, 0, stream>>>(Abuf, dis, b2, out, n);
    k_agg2_edges<<<cdiv((long long)E * 10, 256), 256, 0, stream>>>(Abuf, dis, srcv, dstv, out, E);
}

// Round 3
// 888.072 us; speedup vs baseline: 3.7739x; 3.7739x over previous
//
#include <hip/hip_runtime.h>
#include <cstddef>

// ---------------------------------------------------------------------------
// FastGCN round 2 (resubmit after GPU acquisition timeout):
// CSR-by-dst gather instead of f32 atomics.
//   1. deg count (int atomics)            -> cnt
//   2. dis = rsqrt(deg+1)
//   3. exclusive scan of cnt              -> rowstart   (3-kernel scan)
//   4. scatter edges by dst (int atomics) -> esrc, enorm; cursor ends == deg
//   5. H1 = x@W1                 (row-per-thread GEMM, VGPR acc)
//   6. agg1: wave per dst, gather+reduce, fused bias+relu -> X2
//   7. H2 = X2@W2
//   8. agg2: wave per dst, gather+reduce, fused bias      -> out
// ---------------------------------------------------------------------------

__global__ __launch_bounds__(256) void k_deg(const int* __restrict__ dst,
                                             int* __restrict__ cnt, int E) {
    int e = blockIdx.x * 256 + threadIdx.x;
    if (e < E) atomicAdd(&cnt[dst[e]], 1);
}

__global__ __launch_bounds__(256) void k_dis(const int* __restrict__ cnt,
                                             float* __restrict__ dis, int n) {
    int i = blockIdx.x * 256 + threadIdx.x;
    if (i < n) dis[i] = rsqrtf((float)(cnt[i] + 1));   // +1 = self-loop
}

// exclusive scan, stage 1: per-block scan (block=256), block totals -> bsum
__global__ __launch_bounds__(256) void k_scan_block(const int* __restrict__ cnt,
                                                    int* __restrict__ rowstart,
                                                    int* __restrict__ bsum, int n) {
    __shared__ int sm[256];
    int i = blockIdx.x * 256 + threadIdx.x;
    int v = (i < n) ? cnt[i] : 0;
    sm[threadIdx.x] = v;
    __syncthreads();
    for (int ofs = 1; ofs < 256; ofs <<= 1) {
        int t = (threadIdx.x >= (unsigned)ofs) ? sm[threadIdx.x - ofs] : 0;
        __syncthreads();
        sm[threadIdx.x] += t;
        __syncthreads();
    }
    if (i < n) rowstart[i] = sm[threadIdx.x] - v;        // exclusive within block
    if (threadIdx.x == 255) bsum[blockIdx.x] = sm[255];  // block total
}

// stage 2: single block, exclusive scan of block totals (chunked, carry)
__global__ __launch_bounds__(1024) void k_scan_top(int* __restrict__ bsum, int nb) {
    __shared__ int sm[1024];
    __shared__ int carry;
    if (threadIdx.x == 0) carry = 0;
    __syncthreads();
    for (int base = 0; base < nb; base += 1024) {
        int idx = base + threadIdx.x;
        int v = (idx < nb) ? bsum[idx] : 0;
        sm[threadIdx.x] = v;
        __syncthreads();
        for (int ofs = 1; ofs < 1024; ofs <<= 1) {
            int t = (threadIdx.x >= (unsigned)ofs) ? sm[threadIdx.x - ofs] : 0;
            __syncthreads();
            sm[threadIdx.x] += t;
            __syncthreads();
        }
        if (idx < nb) bsum[idx] = sm[threadIdx.x] - v + carry;  // exclusive + carry
        __syncthreads();
        if (threadIdx.x == 0) carry += sm[1023];
        __syncthreads();
    }
}

// stage 3: add block bases; zero the scatter cursor
__global__ __launch_bounds__(256) void k_scan_add(int* __restrict__ rowstart,
                                                  const int* __restrict__ bsum,
                                                  int* __restrict__ cursor, int n) {
    int i = blockIdx.x * 256 + threadIdx.x;
    if (i < n) {
        rowstart[i] += bsum[blockIdx.x];
        cursor[i] = 0;
    }
}

// scatter edges into CSR slots; cursor[i] ends equal to deg[i] (no self-loop)
__global__ __launch_bounds__(256) void k_scatter(const int* __restrict__ src,
                                                 const int* __restrict__ dst,
                                                 const float* __restrict__ dis,
                                                 const int* __restrict__ rowstart,
                                                 int* __restrict__ cursor,
                                                 int* __restrict__ esrc,
                                                 float* __restrict__ enorm, int E) {
    int e = blockIdx.x * 256 + threadIdx.x;
    if (e >= E) return;
    int s = src[e], d = dst[e];
    int pos = rowstart[d] + atomicAdd(&cursor[d], 1);
    esrc[pos] = s;
    enorm[pos] = dis[s] * dis[d];
}

// One row per thread; W addresses wave-uniform -> scalar loads; acc in VGPRs.
// K fixed at 128. Computes cols [blockIdx.y*MC, +MC) of out[row] (leading dim M).
template <int MC>
__global__ __launch_bounds__(256) void k_gemm(const float* __restrict__ X,
                                              const float* __restrict__ W,
                                              float* __restrict__ out,
                                              int n, int M) {
    int row = blockIdx.x * 256 + threadIdx.x;
    int colbase = blockIdx.y * MC;
    if (row >= n) return;
    const float4* xr = (const float4*)(X + (size_t)row * 128);
    float acc[MC];
#pragma unroll
    for (int j = 0; j < MC; ++j) acc[j] = 0.f;
    for (int k4 = 0; k4 < 32; ++k4) {
        float4 xv = xr[k4];
        const float* w0 = W + (size_t)(k4 * 4) * M + colbase;
#pragma unroll
        for (int j = 0; j < MC; ++j) acc[j] = fmaf(xv.x, w0[j], acc[j]);
#pragma unroll
        for (int j = 0; j < MC; ++j) acc[j] = fmaf(xv.y, w0[M + j], acc[j]);
#pragma unroll
        for (int j = 0; j < MC; ++j) acc[j] = fmaf(xv.z, w0[2 * M + j], acc[j]);
#pragma unroll
        for (int j = 0; j < MC; ++j) acc[j] = fmaf(xv.w, w0[3 * M + j], acc[j]);
    }
    float* o = out + (size_t)row * M + colbase;
#pragma unroll
    for (int j = 0; j < MC; ++j) o[j] = acc[j];
}

// agg layer 1: one wave (64 lanes) per dst node, float2 per lane (128 cols).
// X2 = relu( dis^2*H[i] + sum_e norm*H[src] + b1 )
__global__ __launch_bounds__(256) void k_agg1(const float* __restrict__ H,
                                              const float* __restrict__ dis,
                                              const int* __restrict__ esrc,
                                              const float* __restrict__ enorm,
                                              const int* __restrict__ rowstart,
                                              const int* __restrict__ ecnt,
                                              const float* __restrict__ b1,
                                              float* __restrict__ X2, int n) {
    int wid = (blockIdx.x * 256 + threadIdx.x) >> 6;
    int lane = threadIdx.x & 63;
    if (wid >= n) return;
    int beg = rowstart[wid];
    int end = beg + ecnt[wid];
    float di = dis[wid];
    float2 h = ((const float2*)H)[(size_t)wid * 64 + lane];
    float d2 = di * di;
    float2 acc = make_float2(h.x * d2, h.y * d2);
    for (int e = beg; e < end; ++e) {
        int s = esrc[e];
        float nm = enorm[e];
        float2 hv = ((const float2*)H)[(size_t)s * 64 + lane];
        acc.x = fmaf(nm, hv.x, acc.x);
        acc.y = fmaf(nm, hv.y, acc.y);
    }
    float2 b = ((const float2*)b1)[lane];
    acc.x = fmaxf(acc.x + b.x, 0.f);
    acc.y = fmaxf(acc.y + b.y, 0.f);
    ((float2*)X2)[(size_t)wid * 64 + lane] = acc;
}

// agg layer 2: one wave per dst node, lanes 0..39 hold one col each (40 cols).
// out = dis^2*H2[i] + sum_e norm*H2[src] + b2
__global__ __launch_bounds__(256) void k_agg2(const float* __restrict__ H2,
                                              const float* __restrict__ dis,
                                              const int* __restrict__ esrc,
                                              const float* __restrict__ enorm,
                                              const int* __restrict__ rowstart,
                                              const int* __restrict__ ecnt,
                                              const float* __restrict__ b2,
                                              float* __restrict__ out, int n) {
    int wid = (blockIdx.x * 256 + threadIdx.x) >> 6;
    int lane = threadIdx.x & 63;
    if (wid >= n) return;
    int beg = rowstart[wid];
    int end = beg + ecnt[wid];
    float di = dis[wid];
    bool ok = lane < 40;
    float acc = 0.f;
    if (ok) acc = fmaf(H2[(size_t)wid * 40 + lane], di * di, b2[lane]);
    for (int e = beg; e < end; ++e) {
        int s = esrc[e];
        float nm = enorm[e];
        if (ok) acc = fmaf(nm, H2[(size_t)s * 40 + lane], acc);
    }
    if (ok) out[(size_t)wid * 40 + lane] = acc;
}

static inline int cdiv(long long a, long long b) { return (int)((a + b - 1) / b); }

extern "C" void kernel_launch(void* const* d_in, const int* in_sizes, int n_in,
                              void* d_out, int out_size, void* d_ws, size_t ws_size,
                              hipStream_t stream) {
    const float* x  = (const float*)d_in[0];
    const float* W1 = (const float*)d_in[1];
    const float* b1 = (const float*)d_in[2];
    const float* W2 = (const float*)d_in[3];
    const float* b2 = (const float*)d_in[4];
    const int*   ei = (const int*)d_in[5];

    const int n = in_sizes[0] / 128;   // 170000
    const int E = in_sizes[5] / 2;     // 1200000
    const int* srcv = ei;
    const int* dstv = ei + E;
    float* out = (float*)d_out;

    const int nb = cdiv(n, 256);       // scan blocks

    // workspace carve-up (256B-aligned)
    char* w = (char*)d_ws;
    size_t off = 0;
    auto carve = [&](size_t bytes) {
        void* p = w + off;
        off += (bytes + 255) & ~(size_t)255;
        return p;
    };
    int*   cnt      = (int*)carve((size_t)n * 4);     // deg, then scatter cursor
    float* dis      = (float*)carve((size_t)n * 4);
    int*   rowstart = (int*)carve((size_t)n * 4);
    int*   bsum     = (int*)carve((size_t)nb * 4);
    int*   esrc     = (int*)carve((size_t)E * 4);
    float* enorm    = (float*)carve((size_t)E * 4);
    float* Hbuf     = (float*)carve((size_t)n * 128 * 4);  // H1, then H2
    float* Xbuf     = (float*)carve((size_t)n * 128 * 4);  // X2
    (void)ws_size;

    // degree + norms + CSR build
    hipMemsetAsync(cnt, 0, (size_t)n * 4, stream);
    k_deg<<<cdiv(E, 256), 256, 0, stream>>>(dstv, cnt, E);
    k_dis<<<cdiv(n, 256), 256, 0, stream>>>(cnt, dis, n);
    k_scan_block<<<nb, 256, 0, stream>>>(cnt, rowstart, bsum, n);
    k_scan_top<<<1, 1024, 0, stream>>>(bsum, nb);
    k_scan_add<<<nb, 256, 0, stream>>>(rowstart, bsum, cnt, n);  // cnt -> cursor
    k_scatter<<<cdiv(E, 256), 256, 0, stream>>>(srcv, dstv, dis, rowstart, cnt,
                                                esrc, enorm, E);
    // after scatter, cnt[i] == in-degree of i (CSR segment length)

    // layer 1: H1 = x@W1 ; X2 = relu(agg(H1) + b1)
    dim3 g1(cdiv(n, 256), 128 / 32);
    k_gemm<32><<<g1, 256, 0, stream>>>(x, W1, Hbuf, n, 128);
    k_agg1<<<cdiv(n, 4), 256, 0, stream>>>(Hbuf, dis, esrc, enorm, rowstart, cnt,
                                           b1, Xbuf, n);

    // layer 2: H2 = X2@W2 ; out = agg(H2) + b2
    dim3 g2(cdiv(n, 256), 1);
    k_gemm<40><<<g2, 256, 0, stream>>>(Xbuf, W2, Hbuf, n, 40);
    k_agg2<<<cdiv(n, 4), 256, 0, stream>>>(Hbuf, dis, esrc, enorm, rowstart, cnt,
                                           b2, out, n);
}

// Round 8
// 698.131 us; speedup vs baseline: 4.8006x; 1.2721x over previous
//
#include <hip/hip_runtime.h>
#include <cstddef>

// ---------------------------------------------------------------------------
// FastGCN round 4 (4th resubmit; repeated infra failures): LDS-tiled fp32
// GEMM (kills the 3x fetch amplification of the row-per-thread GEMM).
// CSR-by-dst gather aggregation unchanged.
// ---------------------------------------------------------------------------

__global__ __launch_bounds__(256) void k_deg(const int* __restrict__ dst,
                                             int* __restrict__ cnt, int E) {
    int e = blockIdx.x * 256 + threadIdx.x;
    if (e < E) atomicAdd(&cnt[dst[e]], 1);
}

__global__ __launch_bounds__(256) void k_dis(const int* __restrict__ cnt,
                                             float* __restrict__ dis, int n) {
    int i = blockIdx.x * 256 + threadIdx.x;
    if (i < n) dis[i] = rsqrtf((float)(cnt[i] + 1));   // +1 = self-loop
}

// exclusive scan, stage 1: per-block scan (block=256), block totals -> bsum
__global__ __launch_bounds__(256) void k_scan_block(const int* __restrict__ cnt,
                                                    int* __restrict__ rowstart,
                                                    int* __restrict__ bsum, int n) {
    __shared__ int sm[256];
    int i = blockIdx.x * 256 + threadIdx.x;
    int v = (i < n) ? cnt[i] : 0;
    sm[threadIdx.x] = v;
    __syncthreads();
    for (int ofs = 1; ofs < 256; ofs <<= 1) {
        int t = (threadIdx.x >= (unsigned)ofs) ? sm[threadIdx.x - ofs] : 0;
        __syncthreads();
        sm[threadIdx.x] += t;
        __syncthreads();
    }
    if (i < n) rowstart[i] = sm[threadIdx.x] - v;        // exclusive within block
    if (threadIdx.x == 255) bsum[blockIdx.x] = sm[255];  // block total
}

// stage 2: single block, exclusive scan of block totals (chunked, carry)
__global__ __launch_bounds__(1024) void k_scan_top(int* __restrict__ bsum, int nb) {
    __shared__ int sm[1024];
    __shared__ int carry;
    if (threadIdx.x == 0) carry = 0;
    __syncthreads();
    for (int base = 0; base < nb; base += 1024) {
        int idx = base + threadIdx.x;
        int v = (idx < nb) ? bsum[idx] : 0;
        sm[threadIdx.x] = v;
        __syncthreads();
        for (int ofs = 1; ofs < 1024; ofs <<= 1) {
            int t = (threadIdx.x >= (unsigned)ofs) ? sm[threadIdx.x - ofs] : 0;
            __syncthreads();
            sm[threadIdx.x] += t;
            __syncthreads();
        }
        if (idx < nb) bsum[idx] = sm[threadIdx.x] - v + carry;  // exclusive + carry
        __syncthreads();
        if (threadIdx.x == 0) carry += sm[1023];
        __syncthreads();
    }
}

// stage 3: add block bases; zero the scatter cursor
__global__ __launch_bounds__(256) void k_scan_add(int* __restrict__ rowstart,
                                                  const int* __restrict__ bsum,
                                                  int* __restrict__ cursor, int n) {
    int i = blockIdx.x * 256 + threadIdx.x;
    if (i < n) {
        rowstart[i] += bsum[blockIdx.x];
        cursor[i] = 0;
    }
}

// scatter edges into CSR slots; cursor[i] ends equal to deg[i] (no self-loop)
__global__ __launch_bounds__(256) void k_scatter(const int* __restrict__ src,
                                                 const int* __restrict__ dst,
                                                 const float* __restrict__ dis,
                                                 const int* __restrict__ rowstart,
                                                 int* __restrict__ cursor,
                                                 int* __restrict__ esrc,
                                                 float* __restrict__ enorm, int E) {
    int e = blockIdx.x * 256 + threadIdx.x;
    if (e >= E) return;
    int s = src[e], d = dst[e];
    int pos = rowstart[d] + atomicAdd(&cursor[d], 1);
    esrc[pos] = s;
    enorm[pos] = dis[s] * dis[d];
}

// ---------------------------------------------------------------------------
// LDS-tiled GEMM: out[n,M] = X[n,128] @ W[128,M].
// Block = 256 threads (4 waves), tile = 64 rows. x-tile staged in LDS with
// coalesced float4 loads; wave w owns cols [w*M/4, +M/4) (W reads wave-uniform
// -> scalar loads, L2-resident); lane = row within tile.
// ---------------------------------------------------------------------------
template <int M>
__global__ __launch_bounds__(256) void k_gemm_t(const float* __restrict__ X,
                                                const float* __restrict__ W,
                                                float* __restrict__ out, int n) {
    constexpr int CPW = M / 4;          // cols per wave
    __shared__ float4 xs4[64 * 33];     // 64 rows x 32 float4, pad to 33
    const int tid = threadIdx.x;
    const int rowbase = blockIdx.x * 64;

    // stage x tile: 2048 float4, 8 per thread, fully coalesced
    const float4* Xv = (const float4*)X;
#pragma unroll
    for (int i = 0; i < 8; ++i) {
        int idx = i * 256 + tid;
        int row = idx >> 5, c4 = idx & 31;
        int gr = rowbase + row;
        float4 v = make_float4(0.f, 0.f, 0.f, 0.f);
        if (gr < n) v = Xv[(size_t)gr * 32 + c4];
        xs4[row * 33 + c4] = v;
    }
    __syncthreads();

    const int lane = tid & 63;
    int colbase = (tid >> 6) * CPW;
    colbase = __builtin_amdgcn_readfirstlane(colbase);  // force wave-uniform

    float acc[CPW];
#pragma unroll
    for (int j = 0; j < CPW; ++j) acc[j] = 0.f;

    for (int k4 = 0; k4 < 32; ++k4) {
        float4 xv = xs4[lane * 33 + k4];
        const float* w0 = W + (size_t)(k4 * 4) * M + colbase;
#pragma unroll
        for (int j = 0; j < CPW; ++j) acc[j] = fmaf(xv.x, w0[j], acc[j]);
#pragma unroll
        for (int j = 0; j < CPW; ++j) acc[j] = fmaf(xv.y, w0[M + j], acc[j]);
#pragma unroll
        for (int j = 0; j < CPW; ++j) acc[j] = fmaf(xv.z, w0[2 * M + j], acc[j]);
#pragma unroll
        for (int j = 0; j < CPW; ++j) acc[j] = fmaf(xv.w, w0[3 * M + j], acc[j]);
    }

    int gr = rowbase + lane;
    if (gr < n) {
        float* o = out + (size_t)gr * M + colbase;
#pragma unroll
        for (int j = 0; j < CPW; ++j) o[j] = acc[j];
    }
}

// agg layer 1: one wave (64 lanes) per dst node, float2 per lane (128 cols).
// X2 = relu( dis^2*H[i] + sum_e norm*H[src] + b1 )
__global__ __launch_bounds__(256) void k_agg1(const float* __restrict__ H,
                                              const float* __restrict__ dis,
                                              const int* __restrict__ esrc,
                                              const float* __restrict__ enorm,
                                              const int* __restrict__ rowstart,
                                              const int* __restrict__ ecnt,
                                              const float* __restrict__ b1,
                                              float* __restrict__ X2, int n) {
    int wid = (blockIdx.x * 256 + threadIdx.x) >> 6;
    int lane = threadIdx.x & 63;
    if (wid >= n) return;
    int beg = rowstart[wid];
    int end = beg + ecnt[wid];
    float di = dis[wid];
    float2 h = ((const float2*)H)[(size_t)wid * 64 + lane];
    float d2 = di * di;
    float2 acc = make_float2(h.x * d2, h.y * d2);
    for (int e = beg; e < end; ++e) {
        int s = esrc[e];
        float nm = enorm[e];
        float2 hv = ((const float2*)H)[(size_t)s * 64 + lane];
        acc.x = fmaf(nm, hv.x, acc.x);
        acc.y = fmaf(nm, hv.y, acc.y);
    }
    float2 b = ((const float2*)b1)[lane];
    acc.x = fmaxf(acc.x + b.x, 0.f);
    acc.y = fmaxf(acc.y + b.y, 0.f);
    ((float2*)X2)[(size_t)wid * 64 + lane] = acc;
}

// agg layer 2: one wave per dst node, lanes 0..39 hold one col each (40 cols).
// out = dis^2*H2[i] + sum_e norm*H2[src] + b2
__global__ __launch_bounds__(256) void k_agg2(const float* __restrict__ H2,
                                              const float* __restrict__ dis,
                                              const int* __restrict__ esrc,
                                              const float* __restrict__ enorm,
                                              const int* __restrict__ rowstart,
                                              const int* __restrict__ ecnt,
                                              const float* __restrict__ b2,
                                              float* __restrict__ out, int n) {
    int wid = (blockIdx.x * 256 + threadIdx.x) >> 6;
    int lane = threadIdx.x & 63;
    if (wid >= n) return;
    int beg = rowstart[wid];
    int end = beg + ecnt[wid];
    float di = dis[wid];
    bool ok = lane < 40;
    float acc = 0.f;
    if (ok) acc = fmaf(H2[(size_t)wid * 40 + lane], di * di, b2[lane]);
    for (int e = beg; e < end; ++e) {
        int s = esrc[e];
        float nm = enorm[e];
        if (ok) acc = fmaf(nm, H2[(size_t)s * 40 + lane], acc);
    }
    if (ok) out[(size_t)wid * 40 + lane] = acc;
}

static inline int cdiv(long long a, long long b) { return (int)((a + b - 1) / b); }

extern "C" void kernel_launch(void* const* d_in, const int* in_sizes, int n_in,
                              void* d_out, int out_size, void* d_ws, size_t ws_size,
                              hipStream_t stream) {
    const float* x  = (const float*)d_in[0];
    const float* W1 = (const float*)d_in[1];
    const float* b1 = (const float*)d_in[2];
    const float* W2 = (const float*)d_in[3];
    const float* b2 = (const float*)d_in[4];
    const int*   ei = (const int*)d_in[5];

    const int n = in_sizes[0] / 128;   // 170000
    const int E = in_sizes[5] / 2;     // 1200000
    const int* srcv = ei;
    const int* dstv = ei + E;
    float* out = (float*)d_out;

    const int nb = cdiv(n, 256);       // scan blocks

    // workspace carve-up (256B-aligned)
    char* w = (char*)d_ws;
    size_t off = 0;
    auto carve = [&](size_t bytes) {
        void* p = w + off;
        off += (bytes + 255) & ~(size_t)255;
        return p;
    };
    int*   cnt      = (int*)carve((size_t)n * 4);     // deg, then scatter cursor
    float* dis      = (float*)carve((size_t)n * 4);
    int*   rowstart = (int*)carve((size_t)n * 4);
    int*   bsum     = (int*)carve((size_t)nb * 4);
    int*   esrc     = (int*)carve((size_t)E * 4);
    float* enorm    = (float*)carve((size_t)E * 4);
    float* Hbuf     = (float*)carve((size_t)n * 128 * 4);  // H1, then H2
    float* Xbuf     = (float*)carve((size_t)n * 128 * 4);  // X2
    (void)ws_size;

    // degree + norms + CSR build
    hipMemsetAsync(cnt, 0, (size_t)n * 4, stream);
    k_deg<<<cdiv(E, 256), 256, 0, stream>>>(dstv, cnt, E);
    k_dis<<<cdiv(n, 256), 256, 0, stream>>>(cnt, dis, n);
    k_scan_block<<<nb, 256, 0, stream>>>(cnt, rowstart, bsum, n);
    k_scan_top<<<1, 1024, 0, stream>>>(bsum, nb);
    k_scan_add<<<nb, 256, 0, stream>>>(rowstart, bsum, cnt, n);  // cnt -> cursor
    k_scatter<<<cdiv(E, 256), 256, 0, stream>>>(srcv, dstv, dis, rowstart, cnt,
                                                esrc, enorm, E);
    // after scatter, cnt[i] == in-degree of i (CSR segment length)

    // layer 1: H1 = x@W1 ; X2 = relu(agg(H1) + b1)
    k_gemm_t<128><<<cdiv(n, 64), 256, 0, stream>>>(x, W1, Hbuf, n);
    k_agg1<<<cdiv(n, 4), 256, 0, stream>>>(Hbuf, dis, esrc, enorm, rowstart, cnt,
                                           b1, Xbuf, n);

    // layer 2: H2 = X2@W2 ; out = agg(H2) + b2
    k_gemm_t<40><<<cdiv(n, 64), 256, 0, stream>>>(Xbuf, W2, Hbuf, n);
    k_agg2<<<cdiv(n, 4), 256, 0, stream>>>(Hbuf, dis, esrc, enorm, rowstart, cnt,
                                           b2, out, n);
}